// Round 9
// baseline (186.054 us; speedup 1.0000x reference)
//
#include <hip/hip_runtime.h>

typedef unsigned short u16;
typedef unsigned int u32;
typedef __attribute__((ext_vector_type(8))) short short8;
typedef __attribute__((ext_vector_type(4))) float float4v;
typedef __attribute__((ext_vector_type(4))) unsigned int uint4v;

struct alignas(8) U16x4 { u16 x, y, z, w; };

// fp32 -> bf16 round-to-nearest-even
__device__ __forceinline__ u16 f2b(float f) {
    union { float f; unsigned int u; } v; v.f = f;
    unsigned int r = (v.u >> 16) & 1u;
    v.u += 0x7fffu + r;
    return (u16)(v.u >> 16);
}

__device__ __forceinline__ float b2f(u16 u) {
    union { unsigned int u; float f; } v; v.u = ((u32)u) << 16; return v.f;
}

// pack 2 fp32 -> 2 bf16 (RNE) in one instr
__device__ __forceinline__ u32 cvt_pk_bf16(float lo, float hi) {
    u32 d;
    asm("v_cvt_pk_bf16_f32 %0, %1, %2" : "=v"(d) : "v"(lo), "v"(hi));
    return d;
}

// async global->LDS, 16B per lane; LDS dest = wave-uniform base + lane*16
__device__ __forceinline__ void gld16(const u16* g, u16* l) {
    __builtin_amdgcn_global_load_lds(
        (const __attribute__((address_space(1))) void*)g,
        (__attribute__((address_space(3))) void*)l, 16, 0, 0);
}

// read a short8 fragment from an XOR-swizzled [rows][64] u16 LDS tile.
// chunk cg (16B units within the 128B row) is stored at slot cg^(row&7).
__device__ __forceinline__ short8 frag8(const u16* base, int row, int cg) {
    return *(const short8*)(base + row * 64 + ((cg ^ (row & 7)) << 3));
}

// ---------------------------------------------------------------------------
// prep (ORIGINAL R0 version, proven): id<4096 -> x fp32->bf16;
// id>=4096 -> 32x32 transpose+cvt tile of W[z]. [32][33] pad = conflict-free
// column reads; scalar 4B loads are fully coalesced (128B segments).
// ---------------------------------------------------------------------------
__global__ __launch_bounds__(256) void prep_kernel(
    const float* __restrict__ x, const float* __restrict__ W0,
    const float* __restrict__ W1, const float* __restrict__ W2,
    const float* __restrict__ W3, u16* __restrict__ xb,
    u16* __restrict__ T0, u16* __restrict__ T1,
    u16* __restrict__ T2, u16* __restrict__ T3) {
    __shared__ float tile[32][33];
    int id = blockIdx.x;
    if (id < 4096) {
        size_t i = ((size_t)id * 256 + threadIdx.x) * 4;
        float4 v = *(const float4*)(x + i);
        U16x4 o;
        o.x = f2b(v.x); o.y = f2b(v.y); o.z = f2b(v.z); o.w = f2b(v.w);
        *(U16x4*)(xb + i) = o;
        return;
    }
    int r = id - 4096;
    int z = r >> 10, tl = r & 1023;
    const float* W = (z == 0) ? W0 : (z == 1) ? W1 : (z == 2) ? W2 : W3;
    u16* T = (z == 0) ? T0 : (z == 1) ? T1 : (z == 2) ? T2 : T3;
    int t = threadIdx.x;
    int tx = t & 31, ty = t >> 5;
    int bn = (tl & 31) * 32, bk = (tl >> 5) * 32;
#pragma unroll
    for (int p = 0; p < 4; ++p) {
        int k = ty + p * 8;
        tile[k][tx] = W[(size_t)(bk + k) * 1024 + bn + tx];
    }
    __syncthreads();
#pragma unroll
    for (int p = 0; p < 4; ++p) {
        int n = ty + p * 8;
        T[(size_t)(bn + n) * 1024 + bk + tx] = f2b(tile[tx][n]);
    }
}

// ---------------------------------------------------------------------------
// QKV projection v17 (= v13's qkv, re-landed ALONE for attribution):
// single m97-structure GEMM over STACKED weights. WqT/WkT/WvT contiguous
// -> B = [3072][1024] bf16. M=4096. 128x128 tile, BK=64, 256 thr = 4 waves
// (2x2, 64x64 each), grid = 768 (32 m x 24 n, XCD-swizzled) = 3 blocks/CU.
// LDS 32 KB. Staging economy: 32 KB/k-step for 256 MFMAs (8 MFMA/KB) vs
// v11's 56 KB for 192 (3.4) -- qkv is staging-BW-bound, so this is the lever.
// n-tile never straddles a z boundary -> epilogue z-branch block-uniform.
// ---------------------------------------------------------------------------
__global__ __launch_bounds__(256, 3) void qkv_kernel(
    const u16* __restrict__ X, const u16* __restrict__ WT,
    const float* __restrict__ bq, const float* __restrict__ bk, const float* __restrict__ bv,
    u16* __restrict__ Qo, u16* __restrict__ Ko, u16* __restrict__ VTo) {
    __shared__ __align__(16) u16 As[128 * 64];
    __shared__ __align__(16) u16 Bs[128 * 64];
    int id = blockIdx.x;                       // 768 = 8 xcd * 4 mg * 24 n
    int m = (id & 7) | (((id >> 3) & 3) << 3); // 0..31, id%8 == m%8
    int n = id >> 5;                           // 0..23
    int t = threadIdx.x;
    int m0 = m * 128, n0 = n * 128;
    int lane = t & 63, wid = t >> 6;           // wid 0..3
    int wr = wid >> 1, wc = wid & 1;           // 2x2 wave grid, 64x64 each
    int l16 = lane & 15, quad = lane >> 4;
    int rl = lane >> 3, cs = lane & 7;

    // staging roles: waves 0-1 -> As (16 groups), waves 2-3 -> Bs (16 groups)
    const u16* gsrc = (wid < 2) ? X : WT;
    int gbase = (wid < 2) ? m0 : n0;
    u16* ldst = (wid < 2) ? As : Bs;
    int h8 = wid & 1;

    float4v acc[4][4];
    float4v zero4 = {0.f, 0.f, 0.f, 0.f};
#pragma unroll
    for (int i = 0; i < 4; ++i)
#pragma unroll
        for (int j = 0; j < 4; ++j) acc[i][j] = zero4;

    for (int k0 = 0; k0 < 1024; k0 += 64) {
        __syncthreads();
#pragma unroll
        for (int p = 0; p < 8; ++p) {
            int q = h8 * 8 + p;              // 0..15 within the tile
            int row = q * 8 + rl;            // 0..127
            int c = cs ^ (row & 7);
            gld16(gsrc + (size_t)(gbase + row) * 1024 + k0 + c * 8, ldst + q * 512);
        }
        __syncthreads();   // vmcnt(0) drained -> both tiles ready
#pragma unroll
        for (int ks = 0; ks < 64; ks += 32) {
            int cg = (ks >> 3) + quad;
            short8 af[4], bf[4];
#pragma unroll
            for (int i = 0; i < 4; ++i)
                af[i] = frag8(As, wr * 64 + i * 16 + l16, cg);
#pragma unroll
            for (int j = 0; j < 4; ++j)
                bf[j] = frag8(Bs, wc * 64 + j * 16 + l16, cg);
#pragma unroll
            for (int i = 0; i < 4; ++i)
#pragma unroll
                for (int j = 0; j < 4; ++j)
                    acc[i][j] = __builtin_amdgcn_mfma_f32_16x16x32_bf16(
                        af[i], bf[j], acc[i][j], 0, 0, 0);
        }
    }

    // epilogue: z uniform per block (n-tile within one 1024-col z-slab)
    int z = n >> 3;
    const float QSCALE = 0.18033688011112042f;   // 0.125 * log2(e)
#pragma unroll
    for (int j = 0; j < 4; ++j) {
        int n1 = n0 + wc * 64 + j * 16 + l16;
        int col = n1 & 1023;
        float bcol = (z == 0) ? bq[col] : (z == 1) ? bk[col] : bv[col];
#pragma unroll
        for (int i = 0; i < 4; ++i) {
            int mbase = m0 + wr * 64 + i * 16 + quad * 4;
            if (z == 0) {
#pragma unroll
                for (int r = 0; r < 4; ++r)
                    Qo[(size_t)(mbase + r) * 1024 + col] =
                        f2b((acc[i][j][r] + bcol) * QSCALE);
            } else if (z == 1) {
#pragma unroll
                for (int r = 0; r < 4; ++r)
                    Ko[(size_t)(mbase + r) * 1024 + col] =
                        f2b(acc[i][j][r] + bcol);
            } else {
                // V^T [B,H,dk,S]: rows r are consecutive s -> 8B vector store
                int bidx = mbase >> 11, s = mbase & 2047;
                size_t base =
                    ((size_t)((bidx * 16 + (col >> 6)) * 64 + (col & 63))) * 2048 + s;
                U16x4 pk;
                pk.x = f2b(acc[i][j][0] + bcol);
                pk.y = f2b(acc[i][j][1] + bcol);
                pk.z = f2b(acc[i][j][2] + bcol);
                pk.w = f2b(acc[i][j][3] + bcol);
                *(U16x4*)(VTo + base) = pk;
            }
        }
    }
}

// ---------------------------------------------------------------------------
// Output projection v12 (proven): FUSED COMBINE, serial staging.
// grid = 1024 flat, XCD-swizzled, LDS 20 KB -> 4 blocks/CU. 4 waves.
// ---------------------------------------------------------------------------
__global__ __launch_bounds__(256, 4) void oproj_kernel(const u16* __restrict__ Op,
                                                       const float* __restrict__ lp,
                                                       const u16* __restrict__ WoT,
                                                       const float* __restrict__ bias,
                                                       float* __restrict__ out) {
    __shared__ __align__(16) u16 As[64 * 64];
    __shared__ __align__(16) u16 Bs[64 * 64];
    __shared__ float invs[64][16];             // 1/(l0+l1) per (row, head)
    int id = blockIdx.x;                       // 1024 = 8 xcd * 8 mgrp * 16 n
    int m = (id & 7) | (((id >> 3) & 7) << 3); // 0..63, id%8 == m%8
    int n = id >> 6;                           // 0..15
    int t = threadIdx.x;
    int m0 = m * 64, n0 = n * 64;
    int lane = t & 63, wid = t >> 6;           // wid 0..3
    int l16 = lane & 15, quad = lane >> 4;
    int rl = lane >> 3, cs = lane & 7;

#pragma unroll
    for (int e = t; e < 1024; e += 256) {
        int row = e >> 4, h = e & 15;
        int qg = (m0 + row) * 16 + h;
        invs[row][h] = 1.0f / (lp[qg] + lp[65536 + qg]);
    }

    float4v acc[4];
    float4v zero4 = {0.f, 0.f, 0.f, 0.f};
#pragma unroll
    for (int i = 0; i < 4; ++i) acc[i] = zero4;

    for (int k0 = 0; k0 < 1024; k0 += 64) {
        __syncthreads();
#pragma unroll
        for (int p = 0; p < 2; ++p) {
            int blk = wid * 2 + p;           // 0..7
            int row = blk * 8 + rl;          // 0..63
            int c = cs ^ (row & 7);
            gld16(WoT + (size_t)(n0 + row) * 1024 + k0 + c * 8, Bs + blk * 512);
        }
        int h = k0 >> 6;                     // one head per 64-k tile
#pragma unroll
        for (int p = 0; p < 2; ++p) {
            int blk = wid * 2 + p;           // 0..7
            int row = blk * 8 + rl;          // 0..63
            size_t goff = (size_t)(m0 + row) * 1024 + k0 + cs * 8;
            short8 o0 = *(const short8*)(Op + goff);
            short8 o1 = *(const short8*)(Op + 4194304 + goff);
            float iv = invs[row][h];
            uint4v w;
#pragma unroll
            for (int q2 = 0; q2 < 4; ++q2) {
                float a = (b2f((u16)o0[q2 * 2]) + b2f((u16)o1[q2 * 2])) * iv;
                float bb = (b2f((u16)o0[q2 * 2 + 1]) + b2f((u16)o1[q2 * 2 + 1])) * iv;
                w[q2] = cvt_pk_bf16(a, bb);
            }
            *(uint4v*)(As + row * 64 + ((cs ^ (row & 7)) << 3)) = w;
        }
        __syncthreads();
#pragma unroll
        for (int ks = 0; ks < 64; ks += 32) {
            int cg = (ks >> 3) + quad;
            short8 af[4];
#pragma unroll
            for (int i = 0; i < 4; ++i) af[i] = frag8(As, i * 16 + l16, cg);
            short8 bf = frag8(Bs, wid * 16 + l16, cg);
#pragma unroll
            for (int i = 0; i < 4; ++i)
                acc[i] = __builtin_amdgcn_mfma_f32_16x16x32_bf16(
                    af[i], bf, acc[i], 0, 0, 0);
        }
    }

    int n1 = n0 + wid * 16 + l16;
    float bvl = bias[n1];
#pragma unroll
    for (int i = 0; i < 4; ++i) {
        int mbase = m0 + i * 16 + quad * 4;
#pragma unroll
        for (int r = 0; r < 4; ++r)
            out[(size_t)(mbase + r) * 1024 + n1] = acc[i][r] + bvl;
    }
}

// ---------------------------------------------------------------------------
// Flash attention v15 (proven): register-P + counted-vmcnt split-wait
// pipeline. K,K,V,V stage order; vmcnt(2) before QK, vmcnt(4) before PV
// (next tile's loads stay outstanding across the barrier).
// ---------------------------------------------------------------------------
__global__ __launch_bounds__(256, 4) void flash_kernel(const u16* __restrict__ Q,
                                                       const u16* __restrict__ Kn,
                                                       const u16* __restrict__ VT,
                                                       u16* __restrict__ Opart,
                                                       float* __restrict__ lpart) {
    __shared__ __align__(16) u16 Ks[2][64 * 64];   // [key-slot][dim] swizzled, key-permuted rows
    __shared__ __align__(16) u16 Vs[2][64 * 64];   // [dim][key] swizzled, natural key order

    int id = blockIdx.x;                        // 1024
    int bh = (id & 7) | (((id >> 3) & 3) << 3); // id%8 == bh%8
    int rest = id >> 5;                         // 0..31
    int qb = rest & 15, kvz = rest >> 4;
    int b = bh >> 4, h = bh & 15;
    int t = threadIdx.x;
    int wid = t >> 6, lane = t & 63;            // wid 0..3
    int l16 = lane & 15, quad = lane >> 4;
    int rl = lane >> 3, cs = lane & 7;
    int q0 = qb * 128 + wid * 32;               // wave's first query
    size_t kbase = (size_t)(b * 2048) * 1024 + h * 64;
    size_t vbase = (size_t)(bh * 64) * 2048;
    int kv0 = kvz * 1024;

    // Q B-fragments (n=q, k=dim), direct from global (64B/row coalesced)
    short8 qf[2][2];
#pragma unroll
    for (int j = 0; j < 2; ++j)
#pragma unroll
        for (int kk = 0; kk < 2; ++kk)
            qf[j][kk] = *(const short8*)(
                Q + ((size_t)(b * 2048 + q0 + j * 16 + l16)) * 1024 + h * 64 +
                kk * 32 + quad * 8);

    float4v oacc[2][4];
    float4v den[2];
    float4v zero4 = {0.f, 0.f, 0.f, 0.f};
    const short8 ones8 = {(short)0x3F80, (short)0x3F80, (short)0x3F80, (short)0x3F80,
                          (short)0x3F80, (short)0x3F80, (short)0x3F80, (short)0x3F80};
#pragma unroll
    for (int ip = 0; ip < 2; ++ip) {
        den[ip] = zero4;
#pragma unroll
        for (int jd = 0; jd < 4; ++jd) oacc[ip][jd] = zero4;
    }

#define STAGE_K(buf, kv)                                                      \
    {                                                                         \
        _Pragma("unroll") for (int p2 = 0; p2 < 2; ++p2) {                    \
            int p = wid * 2 + p2;                                             \
            int row = p * 8 + rl;                                             \
            int c = cs ^ (row & 7);                                           \
            int key = (((row >> 4) & 1) << 5) | (((row >> 2) & 3) << 3) |     \
                      (((row >> 5) & 1) << 2) | (row & 3);                    \
            gld16(Kn + kbase + (size_t)((kv) + key) * 1024 + c * 8,           \
                  &Ks[buf][p * 512]);                                         \
        }                                                                     \
    }
#define STAGE_V(buf, kv)                                                      \
    {                                                                         \
        _Pragma("unroll") for (int p2 = 0; p2 < 2; ++p2) {                    \
            int p = wid * 2 + p2;                                             \
            int row = p * 8 + rl;                                             \
            int c = cs ^ (row & 7);                                           \
            gld16(VT + vbase + (size_t)row * 2048 + (kv) + c * 8,             \
                  &Vs[buf][p * 512]);                                         \
        }                                                                     \
    }

    STAGE_K(0, kv0);
    STAGE_V(0, kv0);

    for (int kvi = 0; kvi < 16; ++kvi) {
        int buf = kvi & 1;
        // K(kvi) landed; V(kvi) may still be in flight
        asm volatile("s_waitcnt vmcnt(2)" ::: "memory");
        __builtin_amdgcn_s_barrier();
        __builtin_amdgcn_sched_barrier(0);
        bool stage = (kvi + 1 < 16);
        if (stage) {
            // all waves passed PV(kvi-1) on buf^1 -> safe to overwrite
            STAGE_K(buf ^ 1, kv0 + (kvi + 1) * 64);
            STAGE_V(buf ^ 1, kv0 + (kvi + 1) * 64);
        }

        // S^T = K * Q^T per 16-key tile i; exp2 + cvt_pk pack in-register.
        u32 pw[2][4][2];
#pragma unroll
        for (int i = 0; i < 4; ++i) {
            float4v s0 = zero4, s1 = zero4;
            __builtin_amdgcn_s_setprio(1);
#pragma unroll
            for (int kk = 0; kk < 2; ++kk) {
                short8 kf = frag8(&Ks[buf][0], i * 16 + l16, kk * 4 + quad);
                s0 = __builtin_amdgcn_mfma_f32_16x16x32_bf16(kf, qf[0][kk], s0, 0, 0, 0);
                s1 = __builtin_amdgcn_mfma_f32_16x16x32_bf16(kf, qf[1][kk], s1, 0, 0, 0);
            }
            __builtin_amdgcn_s_setprio(0);
#pragma unroll
            for (int j = 0; j < 2; ++j) {
                float4v s = (j == 0) ? s0 : s1;
                float e0f = __builtin_amdgcn_exp2f(s[0]);
                float e1f = __builtin_amdgcn_exp2f(s[1]);
                float e2f = __builtin_amdgcn_exp2f(s[2]);
                float e3f = __builtin_amdgcn_exp2f(s[3]);
                pw[j][i][0] = cvt_pk_bf16(e0f, e1f);
                pw[j][i][1] = cvt_pk_bf16(e2f, e3f);
            }
        }

        // V(kvi) landed; tile(kvi+1) loads stay in flight across barrier
        if (stage) {
            asm volatile("s_waitcnt vmcnt(4)" ::: "memory");
        } else {
            asm volatile("s_waitcnt vmcnt(0)" ::: "memory");
        }
        __builtin_amdgcn_s_barrier();
        __builtin_amdgcn_sched_barrier(0);

        // O += P @ V ; den += P @ ones (pf from registers via key-perm).
        __builtin_amdgcn_s_setprio(1);
#pragma unroll
        for (int kk = 0; kk < 2; ++kk) {
            int cg = kk * 4 + quad;
            short8 vf[4];
#pragma unroll
            for (int jd = 0; jd < 4; ++jd)
                vf[jd] = frag8(&Vs[buf][0], jd * 16 + l16, cg);
#pragma unroll
            for (int j = 0; j < 2; ++j) {
                union { uint4v u; short8 s; } pu;
                pu.u = (uint4v){pw[j][kk][0], pw[j][kk][1],
                                pw[j][2 + kk][0], pw[j][2 + kk][1]};
#pragma unroll
                for (int jd = 0; jd < 4; ++jd)
                    oacc[j][jd] = __builtin_amdgcn_mfma_f32_16x16x32_bf16(
                        pu.s, vf[jd], oacc[j][jd], 0, 0, 0);
                den[j] = __builtin_amdgcn_mfma_f32_16x16x32_bf16(
                    pu.s, ones8, den[j], 0, 0, 0);
            }
        }
        __builtin_amdgcn_s_setprio(0);
    }
#undef STAGE_K
#undef STAGE_V

    // epilogue: write bf16 numerator partials + fp32 denominator partials.
    size_t obase = (size_t)kvz * 4194304;      // [kvz][4096][1024] bf16
#pragma unroll
    for (int ip = 0; ip < 2; ++ip)
#pragma unroll
        for (int r = 0; r < 4; ++r) {
            int q = q0 + ip * 16 + quad * 4 + r;
#pragma unroll
            for (int jd = 0; jd < 4; ++jd)
                Opart[obase + ((size_t)(b * 2048 + q)) * 1024 + h * 64 +
                      jd * 16 + l16] = f2b(oacc[ip][jd][r]);
        }
    if (l16 == 0) {
#pragma unroll
        for (int j = 0; j < 2; ++j)
#pragma unroll
            for (int r = 0; r < 4; ++r) {
                int q = q0 + j * 16 + quad * 4 + r;
                lpart[kvz * 65536 + (b * 2048 + q) * 16 + h] = den[j][r];
            }
    }
}

// ---------------------------------------------------------------------------
// Launch (4 kernels)
// ---------------------------------------------------------------------------
extern "C" void kernel_launch(void* const* d_in, const int* in_sizes, int n_in,
                              void* d_out, int out_size, void* d_ws, size_t ws_size,
                              hipStream_t stream) {
    const float* x  = (const float*)d_in[0];
    const float* Wq = (const float*)d_in[1];
    const float* bq = (const float*)d_in[2];
    const float* Wk = (const float*)d_in[3];
    const float* bk = (const float*)d_in[4];
    const float* Wv = (const float*)d_in[5];
    const float* bv = (const float*)d_in[6];
    const float* Wo = (const float*)d_in[7];
    const float* bo = (const float*)d_in[8];
    float* out = (float*)d_out;

    char* ws = (char*)d_ws;
    const size_t MB = 1024 * 1024;
    u16* xb  = (u16*)(ws);               //  8 MB: x bf16 [4096,1024]
    u16* wqt = (u16*)(ws + 8 * MB);      //  2 MB: Wq^T bf16  (wqt/wkt/wvt
    u16* wkt = (u16*)(ws + 10 * MB);     //   contiguous -> stacked B [3072][1024])
    u16* wvt = (u16*)(ws + 12 * MB);
    u16* wot = (u16*)(ws + 14 * MB);
    u16* qb_ = (u16*)(ws + 16 * MB);     //  8 MB: Q bf16 (pre-scaled)
    u16* kb_ = (u16*)(ws + 24 * MB);     //  8 MB: K bf16
    u16* vt_ = (u16*)(ws + 32 * MB);     //  8 MB: V^T [B,H,dk,S] bf16
    u16* op_ = (u16*)(ws + 48 * MB);     // 16 MB: O partials bf16 [2][4096][1024]
    float* lp_ = (float*)(ws + 64 * MB); // 0.5 MB: l partials fp32 [2][4096][16]

    prep_kernel<<<8192, 256, 0, stream>>>(x, Wq, Wk, Wv, Wo, xb,
                                          wqt, wkt, wvt, wot);
    qkv_kernel<<<768, 256, 0, stream>>>(xb, wqt, bq, bk, bv,
                                        qb_, kb_, vt_);
    flash_kernel<<<1024, 256, 0, stream>>>(qb_, kb_, vt_, op_, lp_);
    oproj_kernel<<<1024, 256, 0, stream>>>(op_, lp_, wot, bo, out);
}

// Round 10
// 177.352 us; speedup vs baseline: 1.0491x; 1.0491x over previous
//
#include <hip/hip_runtime.h>

typedef unsigned short u16;
typedef unsigned int u32;
typedef __attribute__((ext_vector_type(8))) short short8;
typedef __attribute__((ext_vector_type(4))) float float4v;
typedef __attribute__((ext_vector_type(4))) unsigned int uint4v;

struct alignas(8) U16x4 { u16 x, y, z, w; };

// fp32 -> bf16 round-to-nearest-even
__device__ __forceinline__ u16 f2b(float f) {
    union { float f; unsigned int u; } v; v.f = f;
    unsigned int r = (v.u >> 16) & 1u;
    v.u += 0x7fffu + r;
    return (u16)(v.u >> 16);
}

__device__ __forceinline__ float b2f(u16 u) {
    union { unsigned int u; float f; } v; v.u = ((u32)u) << 16; return v.f;
}

// pack 2 fp32 -> 2 bf16 (RNE) in one instr
__device__ __forceinline__ u32 cvt_pk_bf16(float lo, float hi) {
    u32 d;
    asm("v_cvt_pk_bf16_f32 %0, %1, %2" : "=v"(d) : "v"(lo), "v"(hi));
    return d;
}

// async global->LDS, 16B per lane; LDS dest = wave-uniform base + lane*16
__device__ __forceinline__ void gld16(const u16* g, u16* l) {
    __builtin_amdgcn_global_load_lds(
        (const __attribute__((address_space(1))) void*)g,
        (__attribute__((address_space(3))) void*)l, 16, 0, 0);
}

// read a short8 fragment from an XOR-swizzled [rows][64] u16 LDS tile.
// chunk cg (16B units within the 128B row) is stored at slot cg^(row&7).
__device__ __forceinline__ short8 frag8(const u16* base, int row, int cg) {
    return *(const short8*)(base + row * 64 + ((cg ^ (row & 7)) << 3));
}

// ---------------------------------------------------------------------------
// prep (ORIGINAL, proven in both best runs): id<4096 -> x fp32->bf16;
// id>=4096 -> 32x32 transpose+cvt tile of W[z]. [32][33] pad = conflict-free
// column reads; scalar 4B loads fully coalesced (128B segments).
// [R6 lesson: the "vectorized" variant regressed +7.6 us -- 4-way LDS
//  read conflicts from the [32][36] column access. Do not re-land.]
// ---------------------------------------------------------------------------
__global__ __launch_bounds__(256) void prep_kernel(
    const float* __restrict__ x, const float* __restrict__ W0,
    const float* __restrict__ W1, const float* __restrict__ W2,
    const float* __restrict__ W3, u16* __restrict__ xb,
    u16* __restrict__ T0, u16* __restrict__ T1,
    u16* __restrict__ T2, u16* __restrict__ T3) {
    __shared__ float tile[32][33];
    int id = blockIdx.x;
    if (id < 4096) {
        size_t i = ((size_t)id * 256 + threadIdx.x) * 4;
        float4 v = *(const float4*)(x + i);
        U16x4 o;
        o.x = f2b(v.x); o.y = f2b(v.y); o.z = f2b(v.z); o.w = f2b(v.w);
        *(U16x4*)(xb + i) = o;
        return;
    }
    int r = id - 4096;
    int z = r >> 10, tl = r & 1023;
    const float* W = (z == 0) ? W0 : (z == 1) ? W1 : (z == 2) ? W2 : W3;
    u16* T = (z == 0) ? T0 : (z == 1) ? T1 : (z == 2) ? T2 : T3;
    int t = threadIdx.x;
    int tx = t & 31, ty = t >> 5;
    int bn = (tl & 31) * 32, bk = (tl >> 5) * 32;
#pragma unroll
    for (int p = 0; p < 4; ++p) {
        int k = ty + p * 8;
        tile[k][tx] = W[(size_t)(bk + k) * 1024 + bn + tx];
    }
    __syncthreads();
#pragma unroll
    for (int p = 0; p < 4; ++p) {
        int n = ty + p * 8;
        T[(size_t)(bn + n) * 1024 + bk + tx] = f2b(tile[tx][n]);
    }
}

// ---------------------------------------------------------------------------
// Z-FUSED QKV projection v11 (PINNED): m-tile 64, grid = 512 flat
// (64 m x 8 n), XCD-swizzled. LDS 56 KB -> 2 blocks/CU = 16 waves/CU.
// 512 thr = 8 waves, wave = 64m x 16n x 3z. X A-tile staged once for all
// three GEMMs. [R5+R9 lesson: the m97 128x128 stacked-B restructure
// regressed ~+5 us BOTH times it landed (3 blocks/CU = 12 waves/CU +
// wider B panels lose more to barrier drain / L2 pressure than the fat
// tile gains). Do not re-land.]
// z=0: Q bf16 pre-scaled by 0.125*log2(e); z=1: K bf16; z=2: V^T [B,H,dk,S].
// ---------------------------------------------------------------------------
__global__ __launch_bounds__(512, 4) void qkv_kernel(
    const u16* __restrict__ X,
    const u16* __restrict__ WqT, const u16* __restrict__ WkT, const u16* __restrict__ WvT,
    const float* __restrict__ bq, const float* __restrict__ bk, const float* __restrict__ bv,
    u16* __restrict__ Qo, u16* __restrict__ Ko, u16* __restrict__ VTo) {
    __shared__ __align__(16) u16 As[64 * 64];
    __shared__ __align__(16) u16 Bs[3][128 * 64];
    int id = blockIdx.x;                       // 512 = 8 xcd * 8 mgrp * 8 n
    int m = (id & 7) | (((id >> 3) & 7) << 3); // 0..63, id%8 == m%8
    int n = id >> 6;                           // 0..7
    int t = threadIdx.x;
    int m0 = m * 64, n0 = n * 128;
    int lane = t & 63, wid = t >> 6;           // wid 0..7
    int l16 = lane & 15, quad = lane >> 4;
    int rl = lane >> 3, cs = lane & 7;

    int z_st = (wid - 2) >> 1, half = wid & 1;
    const u16* gsrcB = (z_st == 0) ? WqT : (z_st == 1) ? WkT : WvT;

    float4v acc[3][4];
    float4v zero4 = {0.f, 0.f, 0.f, 0.f};
#pragma unroll
    for (int z = 0; z < 3; ++z)
#pragma unroll
        for (int i = 0; i < 4; ++i) acc[z][i] = zero4;

    for (int k0 = 0; k0 < 1024; k0 += 64) {
        __syncthreads();
        if (wid < 2) {
#pragma unroll
            for (int p = 0; p < 4; ++p) {
                int q = wid * 4 + p;             // 0..7
                int row = q * 8 + rl;            // 0..63
                int c = cs ^ (row & 7);
                gld16(X + (size_t)(m0 + row) * 1024 + k0 + c * 8, As + q * 512);
            }
        } else {
#pragma unroll
            for (int p = 0; p < 8; ++p) {
                int q = half * 8 + p;            // 0..15
                int row = q * 8 + rl;            // 0..127
                int c = cs ^ (row & 7);
                gld16(gsrcB + (size_t)(n0 + row) * 1024 + k0 + c * 8,
                      &Bs[z_st][0] + q * 512);
            }
        }
        __syncthreads();   // vmcnt(0) drained -> all 4 tiles ready
#pragma unroll
        for (int ks = 0; ks < 64; ks += 32) {
            int cg = (ks >> 3) + quad;
            short8 af[4];
#pragma unroll
            for (int i = 0; i < 4; ++i)
                af[i] = frag8(As, i * 16 + l16, cg);
#pragma unroll
            for (int z = 0; z < 3; ++z) {
                short8 bf = frag8(&Bs[z][0], wid * 16 + l16, cg);
#pragma unroll
                for (int i = 0; i < 4; ++i)
                    acc[z][i] = __builtin_amdgcn_mfma_f32_16x16x32_bf16(
                        af[i], bf, acc[z][i], 0, 0, 0);
            }
        }
    }

    const float QSCALE = 0.18033688011112042f;   // 0.125 * log2(e)
    int n1 = n0 + wid * 16 + l16;
    float bql = bq[n1], bkl = bk[n1], bvl = bv[n1];
#pragma unroll
    for (int i = 0; i < 4; ++i) {
        int mbase = m0 + i * 16 + quad * 4;
#pragma unroll
        for (int r = 0; r < 4; ++r) {
            Qo[(size_t)(mbase + r) * 1024 + n1] =
                f2b((acc[0][i][r] + bql) * QSCALE);
            Ko[(size_t)(mbase + r) * 1024 + n1] =
                f2b(acc[1][i][r] + bkl);
        }
        int bidx = mbase >> 11, s = mbase & 2047;
        size_t base =
            ((size_t)((bidx * 16 + (n1 >> 6)) * 64 + (n1 & 63))) * 2048 + s;
        U16x4 pk;
        pk.x = f2b(acc[2][i][0] + bvl);
        pk.y = f2b(acc[2][i][1] + bvl);
        pk.z = f2b(acc[2][i][2] + bvl);
        pk.w = f2b(acc[2][i][3] + bvl);
        *(U16x4*)(VTo + base) = pk;
    }
}

// ---------------------------------------------------------------------------
// Output projection v12 (PINNED): FUSED COMBINE, serial staging.
// grid = 1024 flat, XCD-swizzled, LDS 20 KB -> 4 blocks/CU. 4 waves.
// Reads O partials + l partials; normalizes during A-tile staging; GEMM
// with Wo + bias -> fp32 out. (R4's exact version, in the 178.3 run.)
// ---------------------------------------------------------------------------
__global__ __launch_bounds__(256, 4) void oproj_kernel(const u16* __restrict__ Op,
                                                       const float* __restrict__ lp,
                                                       const u16* __restrict__ WoT,
                                                       const float* __restrict__ bias,
                                                       float* __restrict__ out) {
    __shared__ __align__(16) u16 As[64 * 64];
    __shared__ __align__(16) u16 Bs[64 * 64];
    __shared__ float invs[64][16];             // 1/(l0+l1) per (row, head)
    int id = blockIdx.x;                       // 1024 = 8 xcd * 8 mgrp * 16 n
    int m = (id & 7) | (((id >> 3) & 7) << 3); // 0..63, id%8 == m%8
    int n = id >> 6;                           // 0..15
    int t = threadIdx.x;
    int m0 = m * 64, n0 = n * 64;
    int lane = t & 63, wid = t >> 6;           // wid 0..3
    int l16 = lane & 15, quad = lane >> 4;
    int rl = lane >> 3, cs = lane & 7;

#pragma unroll
    for (int e = t; e < 1024; e += 256) {
        int row = e >> 4, h = e & 15;
        int qg = (m0 + row) * 16 + h;
        invs[row][h] = 1.0f / (lp[qg] + lp[65536 + qg]);
    }

    float4v acc[4];
    float4v zero4 = {0.f, 0.f, 0.f, 0.f};
#pragma unroll
    for (int i = 0; i < 4; ++i) acc[i] = zero4;

    for (int k0 = 0; k0 < 1024; k0 += 64) {
        __syncthreads();
#pragma unroll
        for (int p = 0; p < 2; ++p) {
            int blk = wid * 2 + p;           // 0..7
            int row = blk * 8 + rl;          // 0..63
            int c = cs ^ (row & 7);
            gld16(WoT + (size_t)(n0 + row) * 1024 + k0 + c * 8, Bs + blk * 512);
        }
        int h = k0 >> 6;                     // one head per 64-k tile
#pragma unroll
        for (int p = 0; p < 2; ++p) {
            int blk = wid * 2 + p;           // 0..7
            int row = blk * 8 + rl;          // 0..63
            size_t goff = (size_t)(m0 + row) * 1024 + k0 + cs * 8;
            short8 o0 = *(const short8*)(Op + goff);
            short8 o1 = *(const short8*)(Op + 4194304 + goff);
            float iv = invs[row][h];
            uint4v w;
#pragma unroll
            for (int q2 = 0; q2 < 4; ++q2) {
                float a = (b2f((u16)o0[q2 * 2]) + b2f((u16)o1[q2 * 2])) * iv;
                float bb = (b2f((u16)o0[q2 * 2 + 1]) + b2f((u16)o1[q2 * 2 + 1])) * iv;
                w[q2] = cvt_pk_bf16(a, bb);
            }
            *(uint4v*)(As + row * 64 + ((cs ^ (row & 7)) << 3)) = w;
        }
        __syncthreads();
#pragma unroll
        for (int ks = 0; ks < 64; ks += 32) {
            int cg = (ks >> 3) + quad;
            short8 af[4];
#pragma unroll
            for (int i = 0; i < 4; ++i) af[i] = frag8(As, i * 16 + l16, cg);
            short8 bf = frag8(Bs, wid * 16 + l16, cg);
#pragma unroll
            for (int i = 0; i < 4; ++i)
                acc[i] = __builtin_amdgcn_mfma_f32_16x16x32_bf16(
                    af[i], bf, acc[i], 0, 0, 0);
        }
    }

    int n1 = n0 + wid * 16 + l16;
    float bvl = bias[n1];
#pragma unroll
    for (int i = 0; i < 4; ++i) {
        int mbase = m0 + i * 16 + quad * 4;
#pragma unroll
        for (int r = 0; r < 4; ++r)
            out[(size_t)(mbase + r) * 1024 + n1] = acc[i][r] + bvl;
    }
}

// ---------------------------------------------------------------------------
// Flash attention v11 (PINNED -- R4's exact version, in the 178.3 run):
// register-P via key-permuted K staging, grid 1024, 4-wave blocks, 32 KB
// LDS, 4 blocks/CU = 16 waves/CU. P pack via v_cvt_pk_bf16_f32;
// denominator via ones-MFMA. [v15's counted-vmcnt split-wait measured
// -3 us in one A/B (R6->R7) and +3 us in another (R4 vs R8) -- within
// noise both ways; keep the simpler barrier structure from the best run.]
// ---------------------------------------------------------------------------
__global__ __launch_bounds__(256, 4) void flash_kernel(const u16* __restrict__ Q,
                                                       const u16* __restrict__ Kn,
                                                       const u16* __restrict__ VT,
                                                       u16* __restrict__ Opart,
                                                       float* __restrict__ lpart) {
    __shared__ __align__(16) u16 Ks[2][64 * 64];   // [key-slot][dim] swizzled, key-permuted rows
    __shared__ __align__(16) u16 Vs[2][64 * 64];   // [dim][key] swizzled, natural key order

    int id = blockIdx.x;                        // 1024
    int bh = (id & 7) | (((id >> 3) & 3) << 3); // id%8 == bh%8
    int rest = id >> 5;                         // 0..31
    int qb = rest & 15, kvz = rest >> 4;
    int b = bh >> 4, h = bh & 15;
    int t = threadIdx.x;
    int wid = t >> 6, lane = t & 63;            // wid 0..3
    int l16 = lane & 15, quad = lane >> 4;
    int rl = lane >> 3, cs = lane & 7;
    int q0 = qb * 128 + wid * 32;               // wave's first query
    size_t kbase = (size_t)(b * 2048) * 1024 + h * 64;
    size_t vbase = (size_t)(bh * 64) * 2048;
    int kv0 = kvz * 1024;

    // Q B-fragments (n=q, k=dim), direct from global (64B/row coalesced)
    short8 qf[2][2];
#pragma unroll
    for (int j = 0; j < 2; ++j)
#pragma unroll
        for (int kk = 0; kk < 2; ++kk)
            qf[j][kk] = *(const short8*)(
                Q + ((size_t)(b * 2048 + q0 + j * 16 + l16)) * 1024 + h * 64 +
                kk * 32 + quad * 8);

    float4v oacc[2][4];
    float4v den[2];
    float4v zero4 = {0.f, 0.f, 0.f, 0.f};
    const short8 ones8 = {(short)0x3F80, (short)0x3F80, (short)0x3F80, (short)0x3F80,
                          (short)0x3F80, (short)0x3F80, (short)0x3F80, (short)0x3F80};
#pragma unroll
    for (int ip = 0; ip < 2; ++ip) {
        den[ip] = zero4;
#pragma unroll
        for (int jd = 0; jd < 4; ++jd) oacc[ip][jd] = zero4;
    }

    // cooperative stage of one 64-key K/V tile pair into buffer `buf`:
    // each wave stages groups p = wid*2, wid*2+1 (2 gld16 for K, 2 for V).
    // K rows are key-permuted: LDS row `row` holds global key kv+perm(row),
    // perm(row) = i0*32 + quad*8 + i1*4 + r  (bit shuffle, bijective).
#define STAGE_KV(buf, kv)                                                     \
    {                                                                         \
        _Pragma("unroll") for (int p2 = 0; p2 < 2; ++p2) {                    \
            int p = wid * 2 + p2;                                             \
            int row = p * 8 + rl;                                             \
            int c = cs ^ (row & 7);                                           \
            int key = (((row >> 4) & 1) << 5) | (((row >> 2) & 3) << 3) |     \
                      (((row >> 5) & 1) << 2) | (row & 3);                    \
            gld16(Kn + kbase + (size_t)((kv) + key) * 1024 + c * 8,           \
                  &Ks[buf][p * 512]);                                         \
            gld16(VT + vbase + (size_t)row * 2048 + (kv) + c * 8,             \
                  &Vs[buf][p * 512]);                                         \
        }                                                                     \
    }

    STAGE_KV(0, kv0);

    for (int kvi = 0; kvi < 16; ++kvi) {
        int buf = kvi & 1;
        __syncthreads();   // vmcnt(0): tile kvi landed; prev compute done
        if (kvi + 1 < 16) STAGE_KV(buf ^ 1, kv0 + (kvi + 1) * 64);

        // S^T = K * Q^T per 16-key tile i; exp2 + cvt_pk pack in-register.
        u32 pw[2][4][2];
#pragma unroll
        for (int i = 0; i < 4; ++i) {
            float4v s0 = zero4, s1 = zero4;
            __builtin_amdgcn_s_setprio(1);
#pragma unroll
            for (int kk = 0; kk < 2; ++kk) {
                short8 kf = frag8(&Ks[buf][0], i * 16 + l16, kk * 4 + quad);
                s0 = __builtin_amdgcn_mfma_f32_16x16x32_bf16(kf, qf[0][kk], s0, 0, 0, 0);
                s1 = __builtin_amdgcn_mfma_f32_16x16x32_bf16(kf, qf[1][kk], s1, 0, 0, 0);
            }
            __builtin_amdgcn_s_setprio(0);
#pragma unroll
            for (int j = 0; j < 2; ++j) {
                float4v s = (j == 0) ? s0 : s1;
                float e0f = __builtin_amdgcn_exp2f(s[0]);
                float e1f = __builtin_amdgcn_exp2f(s[1]);
                float e2f = __builtin_amdgcn_exp2f(s[2]);
                float e3f = __builtin_amdgcn_exp2f(s[3]);
                pw[j][i][0] = cvt_pk_bf16(e0f, e1f);
                pw[j][i][1] = cvt_pk_bf16(e2f, e3f);
            }
        }

        // O += P @ V ; den += P @ ones (pf from registers via key-perm).
        __builtin_amdgcn_s_setprio(1);
#pragma unroll
        for (int kk = 0; kk < 2; ++kk) {
            int cg = kk * 4 + quad;
            short8 vf[4];
#pragma unroll
            for (int jd = 0; jd < 4; ++jd)
                vf[jd] = frag8(&Vs[buf][0], jd * 16 + l16, cg);
#pragma unroll
            for (int j = 0; j < 2; ++j) {
                union { uint4v u; short8 s; } pu;
                pu.u = (uint4v){pw[j][kk][0], pw[j][kk][1],
                                pw[j][2 + kk][0], pw[j][2 + kk][1]};
#pragma unroll
                for (int jd = 0; jd < 4; ++jd)
                    oacc[j][jd] = __builtin_amdgcn_mfma_f32_16x16x32_bf16(
                        pu.s, vf[jd], oacc[j][jd], 0, 0, 0);
                den[j] = __builtin_amdgcn_mfma_f32_16x16x32_bf16(
                    pu.s, ones8, den[j], 0, 0, 0);
            }
        }
        __builtin_amdgcn_s_setprio(0);
    }
#undef STAGE_KV

    // epilogue: write bf16 numerator partials + fp32 denominator partials.
    // den C-layout: q = q0 + j*16 + quad*4 + r, identical at every l16.
    size_t obase = (size_t)kvz * 4194304;      // [kvz][4096][1024] bf16
#pragma unroll
    for (int ip = 0; ip < 2; ++ip)
#pragma unroll
        for (int r = 0; r < 4; ++r) {
            int q = q0 + ip * 16 + quad * 4 + r;
#pragma unroll
            for (int jd = 0; jd < 4; ++jd)
                Opart[obase + ((size_t)(b * 2048 + q)) * 1024 + h * 64 +
                      jd * 16 + l16] = f2b(oacc[ip][jd][r]);
        }
    if (l16 == 0) {
#pragma unroll
        for (int j = 0; j < 2; ++j)
#pragma unroll
            for (int r = 0; r < 4; ++r) {
                int q = q0 + j * 16 + quad * 4 + r;
                lpart[kvz * 65536 + (b * 2048 + q) * 16 + h] = den[j][r];
            }
    }
}

// ---------------------------------------------------------------------------
// Launch (4 kernels)
// ---------------------------------------------------------------------------
extern "C" void kernel_launch(void* const* d_in, const int* in_sizes, int n_in,
                              void* d_out, int out_size, void* d_ws, size_t ws_size,
                              hipStream_t stream) {
    const float* x  = (const float*)d_in[0];
    const float* Wq = (const float*)d_in[1];
    const float* bq = (const float*)d_in[2];
    const float* Wk = (const float*)d_in[3];
    const float* bk = (const float*)d_in[4];
    const float* Wv = (const float*)d_in[5];
    const float* bv = (const float*)d_in[6];
    const float* Wo = (const float*)d_in[7];
    const float* bo = (const float*)d_in[8];
    float* out = (float*)d_out;

    char* ws = (char*)d_ws;
    const size_t MB = 1024 * 1024;
    u16* xb  = (u16*)(ws);               //  8 MB: x bf16 [4096,1024]
    u16* wqt = (u16*)(ws + 8 * MB);      //  2 MB: Wq^T bf16
    u16* wkt = (u16*)(ws + 10 * MB);
    u16* wvt = (u16*)(ws + 12 * MB);
    u16* wot = (u16*)(ws + 14 * MB);
    u16* qb_ = (u16*)(ws + 16 * MB);     //  8 MB: Q bf16 (pre-scaled)
    u16* kb_ = (u16*)(ws + 24 * MB);     //  8 MB: K bf16
    u16* vt_ = (u16*)(ws + 32 * MB);     //  8 MB: V^T [B,H,dk,S] bf16
    u16* op_ = (u16*)(ws + 48 * MB);     // 16 MB: O partials bf16 [2][4096][1024]
    float* lp_ = (float*)(ws + 64 * MB); // 0.5 MB: l partials fp32 [2][4096][16]

    prep_kernel<<<8192, 256, 0, stream>>>(x, Wq, Wk, Wv, Wo, xb,
                                          wqt, wkt, wvt, wot);
    qkv_kernel<<<512, 512, 0, stream>>>(xb, wqt, wkt, wvt, bq, bk, bv,
                                        qb_, kb_, vt_);
    flash_kernel<<<1024, 256, 0, stream>>>(qb_, kb_, vt_, op_, lp_);
    oproj_kernel<<<1024, 256, 0, stream>>>(op_, lp_, wot, bo, out);
}